// Round 10
// baseline (363.992 us; speedup 1.0000x reference)
//
#include <hip/hip_runtime.h>
#include <hip/hip_fp16.h>
#include <stdint.h>

#define CH 128
#define OC 64
#define NG 512
#define NBLK 256      // partition blocks
#define NBMAX 4096    // max coarse buckets (nodes/256)
#define PADB 3840     // per-bucket pad reserve (15*256)

typedef unsigned int uint;
typedef unsigned short ushort;
typedef __attribute__((ext_vector_type(8))) _Float16 half8;
typedef __attribute__((ext_vector_type(4))) float floatx4;

__device__ __forceinline__ __half2 h2(uint u) { return *(__half2*)&u; }

// ---------------- bucket histogram, written bucket-major ----------------
__global__ __launch_bounds__(256) void k_hist(const int* __restrict__ dst,
                                              int* __restrict__ bhT,
                                              int E, int NB, int chunk) {
    __shared__ int h[NBMAX];
    int blk = blockIdx.x, tid = threadIdx.x;
    for (int j = tid; j < NB; j += 256) h[j] = 0;
    __syncthreads();
    int lo = blk * chunk, hi = min(E, lo + chunk);
    for (int i = lo + tid; i < hi; i += 256) atomicAdd(&h[dst[i] >> 8], 1);
    __syncthreads();
    for (int j = tid; j < NB; j += 256) bhT[j * NBLK + blk] = h[j];
}

// ---------------- prefix scan (block offsets folded by consumers) ---------
__global__ __launch_bounds__(256) void k_scan1(const int* __restrict__ in,
                                               int* __restrict__ excl,
                                               int* __restrict__ bsums, int T) {
    __shared__ int sd[256];
    int tid = threadIdx.x;
    int base = blockIdx.x * 1024 + tid * 4;
    int v[4];
#pragma unroll
    for (int i = 0; i < 4; i++) v[i] = (base + i < T) ? in[base + i] : 0;
    int tsum = v[0] + v[1] + v[2] + v[3];
    int val = tsum;
    sd[tid] = val; __syncthreads();
    for (int off = 1; off < 256; off <<= 1) {
        int t = (tid >= off) ? sd[tid - off] : 0;
        __syncthreads();
        val += t; sd[tid] = val;
        __syncthreads();
    }
    int run = val - tsum;
#pragma unroll
    for (int i = 0; i < 4; i++) {
        if (base + i < T) excl[base + i] = run;
        run += v[i];
    }
    if (tid == 255) bsums[blockIdx.x] = val;
}

__global__ __launch_bounds__(128) void k_scan2(int* __restrict__ bs, int nb) {
    __shared__ int sd[128];
    int tid = threadIdx.x;
    int v = (tid < nb) ? bs[tid] : 0;
    int val = v;
    sd[tid] = val; __syncthreads();
    for (int off = 1; off < 128; off <<= 1) {
        int t = (tid >= off) ? sd[tid - off] : 0;
        __syncthreads();
        val += t; sd[tid] = val;
        __syncthreads();
    }
    if (tid < nb) bs[tid] = val - v;
}

// ------- partition: packed (src<<8)|(dst&255) into per-(bucket,block) segs ----
__global__ __launch_bounds__(256) void k_part(const int* __restrict__ src,
                                              const int* __restrict__ dst,
                                              const int* __restrict__ off,
                                              const int* __restrict__ boff,
                                              int* __restrict__ ebuf,
                                              int E, int NB, int chunk) {
    __shared__ int cur[NBMAX];
    int blk = blockIdx.x, tid = threadIdx.x;
    for (int j = tid; j < NB; j += 256) {
        int idx = j * NBLK + blk;
        cur[j] = off[idx] + boff[idx >> 10];
    }
    __syncthreads();
    int lo = blk * chunk, hi = min(E, lo + chunk);
    for (int i = lo + tid; i < hi; i += 256) {
        int s = src[i], d = dst[i];
        int pos = atomicAdd(&cur[d >> 8], 1);
        ebuf[pos] = (s << 8) | (d & 255);
    }
}

// --- CSR finalize per bucket: rows padded x16, sentinel fill, meta pack ----
// meta[node] = (padded_row_start << 7) | (padded_deg/16); sentinel src = n.
__global__ __launch_bounds__(256) void k_csr(const int* __restrict__ ebuf,
                                             const int* __restrict__ off,
                                             const int* __restrict__ boff,
                                             int* __restrict__ meta,
                                             float* __restrict__ dinv,
                                             int* __restrict__ ssrc,
                                             int n, int NB, int E) {
    __shared__ int cnt[256], sc[256], cur[256];
    int b = blockIdx.x, tid = threadIdx.x;
    int node0 = b << 8;
    int i0 = b * NBLK;
    int bstart = off[i0] + boff[i0 >> 10];
    int bend = E;
    if (b + 1 < NB) {
        int i1 = (b + 1) * NBLK;
        bend = off[i1] + boff[i1 >> 10];
    }
    int base = bstart + b * PADB;          // padded region start
    int rend = bend + (b + 1) * PADB;      // padded region end
    for (int i = base + tid; i < rend; i += 256) ssrc[i] = n;  // sentinel init
    cnt[tid] = 0;
    __syncthreads();
    for (int i = bstart + tid; i < bend; i += 256)
        atomicAdd(&cnt[ebuf[i] & 255], 1);
    __syncthreads();
    int v = cnt[tid];
    int degp = (v + 15) & ~15;
    int val = degp;
    sc[tid] = val; __syncthreads();
    for (int o = 1; o < 256; o <<= 1) {
        int t = (tid >= o) ? sc[tid - o] : 0;
        __syncthreads();
        val += t; sc[tid] = val;
        __syncthreads();
    }
    int excl = val - degp;
    int node = node0 + tid;
    if (node < n) {
        meta[node] = ((base + excl) << 7) | (degp >> 4);
        dinv[node] = rsqrtf((float)v + 1.0f);
    }
    cur[tid] = base + excl;
    __syncthreads();
    for (int i = bstart + tid; i < bend; i += 256) {
        int e = ebuf[i];
        int pos = atomicAdd(&cur[e & 255], 1);
        ssrc[pos] = e >> 8;
    }
}

// -- fused: x->f16 pre-scaled (+sentinels) | Wt transp | Wc,bc | zero q/cnt --
__global__ __launch_bounds__(256) void k_cvtprep(const float* __restrict__ x,
                                                 const float* __restrict__ dinv,
                                                 const float* __restrict__ W1,
                                                 const float* __restrict__ W2,
                                                 const float* __restrict__ b2,
                                                 const float* __restrict__ Wfc,
                                                 const float* __restrict__ bfc,
                                                 ushort* __restrict__ xb,
                                                 ushort* __restrict__ yb,
                                                 ushort* __restrict__ Wt,
                                                 float* __restrict__ Wc,
                                                 float* __restrict__ bc,
                                                 float* __restrict__ q,
                                                 float* __restrict__ cnt,
                                                 int n, int cvtBlocks) {
    int bid = blockIdx.x, tid = threadIdx.x;
    if (bid < cvtBlocks) {
        int i = (bid * 256 + tid) * 4;
        if (i < n * CH) {
            float d = dinv[i >> 7];
            float4 v = *(const float4*)(x + i);
            __half2 h0 = __floats2half2_rn(v.x * d, v.y * d);
            __half2 h1v = __floats2half2_rn(v.z * d, v.w * d);
            uint2 o;
            o.x = *(uint*)&h0; o.y = *(uint*)&h1v;
            *(uint2*)(xb + i) = o;
        }
        if (bid == 0 && tid < CH) {
            xb[(size_t)n * CH + tid] = 0;    // sentinel rows
            yb[(size_t)n * CH + tid] = 0;
        }
        return;
    }
    int t = (bid - cvtBlocks) * 256 + tid;
    int pt = (gridDim.x - cvtBlocks) * 256;
    for (int z = t; z < NG * CH; z += pt) q[z] = 0.f;
    for (int z = t; z < NG; z += pt) cnt[z] = 0.f;
    if (t < CH * CH) {
        int nc = t >> 7, k = t & 127;
        Wt[nc * CH + k] = __half_as_ushort(__float2half(W1[k * CH + nc]));
    } else if (t < CH * CH + CH * OC) {
        int u = t - CH * CH;
        int k = u >> 6, o = u & 63;
        float acc = 0.f;
        for (int j = 0; j < CH; j++) acc += W2[k * CH + j] * Wfc[j * OC + o];
        Wc[u] = acc;
    } else if (t < CH * CH + CH * OC + OC) {
        int o = t - CH * CH - CH * OC;
        float acc = bfc[o];
        for (int j = 0; j < CH; j++) acc += b2[j] * Wfc[j * OC + o];
        bc[o] = acc;
    }
}

// ---- fused agg1 + GEMM: gather y-rows into LDS, then MFMA -> h1s ----
// y[node] = dinv*(sum Hs[src] + Hs[node]); h1s[r] = dinv[r]*relu(y*W1+b1).
__global__ __launch_bounds__(256) void k_aggemm(const ushort* __restrict__ Hs,
                                                const int* __restrict__ meta,
                                                const int* __restrict__ ssrc,
                                                const float* __restrict__ dinv,
                                                const ushort* __restrict__ Wt,
                                                const float* __restrict__ bias,
                                                ushort* __restrict__ H, int n) {
    __shared__ __align__(16) ushort As[64][136];
    int tid = threadIdx.x;
    int w = tid >> 6, lane = tid & 63;
    int sub = lane >> 4, li = lane & 15;
    int c = li * 8;
    int r0 = blockIdx.x * 64;
    // ---- gather phase: wave w fills rows w*16 .. w*16+15 ----
    for (int i = 0; i < 16; ++i) {
        int row = (w << 4) + i;
        int node = r0 + row;
        __half2 A0, A1, A2, A3;
        A0 = A1 = A2 = A3 = __floats2half2_rn(0.f, 0.f);
        float d = 0.f;
        if (node < n) {
            d = dinv[node];
            if (sub == 0) {
                uint4 sv = *(const uint4*)(Hs + (size_t)node * CH + c);
                A0 = h2(sv.x); A1 = h2(sv.y); A2 = h2(sv.z); A3 = h2(sv.w);
            }
            int mv = meta[node];
            int e0 = mv >> 7;
            int iters = mv & 127;
            for (int it = 0; it < iters; ++it) {
                int e = e0 + (it << 4) + sub;
                int s0 = ssrc[e];
                int s1 = ssrc[e + 4];
                int s2 = ssrc[e + 8];
                int s3 = ssrc[e + 12];
                uint4 g0 = *(const uint4*)(Hs + (size_t)s0 * CH + c);
                uint4 g1 = *(const uint4*)(Hs + (size_t)s1 * CH + c);
                uint4 g2 = *(const uint4*)(Hs + (size_t)s2 * CH + c);
                uint4 g3 = *(const uint4*)(Hs + (size_t)s3 * CH + c);
                A0 = __hadd2(A0, __hadd2(__hadd2(h2(g0.x), h2(g1.x)), __hadd2(h2(g2.x), h2(g3.x))));
                A1 = __hadd2(A1, __hadd2(__hadd2(h2(g0.y), h2(g1.y)), __hadd2(h2(g2.y), h2(g3.y))));
                A2 = __hadd2(A2, __hadd2(__hadd2(h2(g0.z), h2(g1.z)), __hadd2(h2(g2.z), h2(g3.z))));
                A3 = __hadd2(A3, __hadd2(__hadd2(h2(g0.w), h2(g1.w)), __hadd2(h2(g2.w), h2(g3.w))));
            }
        }
        float2 f0 = __half22float2(A0);
        float2 f1 = __half22float2(A1);
        float2 f2 = __half22float2(A2);
        float2 f3 = __half22float2(A3);
        float v0 = f0.x, v1 = f0.y, v2 = f1.x, v3 = f1.y;
        float v4 = f2.x, v5 = f2.y, v6 = f3.x, v7 = f3.y;
        v0 += __shfl_xor(v0, 16); v0 += __shfl_xor(v0, 32);
        v1 += __shfl_xor(v1, 16); v1 += __shfl_xor(v1, 32);
        v2 += __shfl_xor(v2, 16); v2 += __shfl_xor(v2, 32);
        v3 += __shfl_xor(v3, 16); v3 += __shfl_xor(v3, 32);
        v4 += __shfl_xor(v4, 16); v4 += __shfl_xor(v4, 32);
        v5 += __shfl_xor(v5, 16); v5 += __shfl_xor(v5, 32);
        v6 += __shfl_xor(v6, 16); v6 += __shfl_xor(v6, 32);
        v7 += __shfl_xor(v7, 16); v7 += __shfl_xor(v7, 32);
        if (sub == 0) {
            __half2 o0 = __floats2half2_rn(v0 * d, v1 * d);
            __half2 o1 = __floats2half2_rn(v2 * d, v3 * d);
            __half2 o2 = __floats2half2_rn(v4 * d, v5 * d);
            __half2 o3 = __floats2half2_rn(v6 * d, v7 * d);
            uint4 o;
            o.x = *(uint*)&o0; o.y = *(uint*)&o1;
            o.z = *(uint*)&o2; o.w = *(uint*)&o3;
            *(uint4*)&As[row][c] = o;
        }
    }
    __syncthreads();
    // ---- MFMA phase: wave w computes rows w*16..w*16+15 ----
    int qm = lane & 15, quad = lane >> 4;
    floatx4 acc[8];
#pragma unroll
    for (int nt = 0; nt < 8; nt++) acc[nt] = (floatx4){0.f, 0.f, 0.f, 0.f};
#pragma unroll
    for (int ks = 0; ks < 4; ks++) {
        int k0 = ks * 32 + quad * 8;
        half8 va = *(const half8*)&As[(w << 4) + qm][k0];
#pragma unroll
        for (int nt = 0; nt < 8; nt++) {
            half8 bfr = *(const half8*)(Wt + (nt * 16 + qm) * CH + k0);
            acc[nt] = __builtin_amdgcn_mfma_f32_16x16x32_f16(va, bfr, acc[nt], 0, 0, 0);
        }
    }
#pragma unroll
    for (int reg = 0; reg < 4; reg++) {
        int r = r0 + (w << 4) + quad * 4 + reg;
        if (r >= n) continue;
        float dd = dinv[r];
#pragma unroll
        for (int nt = 0; nt < 8; nt++) {
            int cidx = nt * 16 + qm;
            float val = fmaxf(acc[nt][reg] + bias[cidx], 0.f) * dd;
            H[(size_t)r * CH + cidx] = __half_as_ushort(__float2half(val));
        }
    }
}

// ---- fused agg2 + pool: z never materialized; fp32 per-graph accumulation --
// pooled[g] += dinv[d]*(sum_e Hs[src] + Hs[d]) for d in g (batch sorted).
__global__ __launch_bounds__(256) void k_agg2pool(const ushort* __restrict__ Hs,
                                                  const int* __restrict__ meta,
                                                  const int* __restrict__ ssrc,
                                                  const float* __restrict__ dinv,
                                                  const int* __restrict__ batch,
                                                  float* __restrict__ Qs,
                                                  float* __restrict__ cnt, int n) {
    int tid = threadIdx.x;
    int w = tid >> 6, lane = tid & 63;
    int sub = lane >> 4, li = lane & 15;
    int c = li * 8;
    int base = (blockIdx.x * 4 + w) * 8;
    if (base >= n) return;
    int end = min(n, base + 8);
    float p0 = 0.f, p1 = 0.f, p2 = 0.f, p3 = 0.f;
    float p4 = 0.f, p5 = 0.f, p6 = 0.f, p7 = 0.f;
    int curg = batch[base], rc = 0;
    for (int node = base; node < end; ++node) {
        int g = batch[node];
        if (g != curg) {
            if (sub == 0) {
                atomicAdd(&Qs[curg * CH + c + 0], p0);
                atomicAdd(&Qs[curg * CH + c + 1], p1);
                atomicAdd(&Qs[curg * CH + c + 2], p2);
                atomicAdd(&Qs[curg * CH + c + 3], p3);
                atomicAdd(&Qs[curg * CH + c + 4], p4);
                atomicAdd(&Qs[curg * CH + c + 5], p5);
                atomicAdd(&Qs[curg * CH + c + 6], p6);
                atomicAdd(&Qs[curg * CH + c + 7], p7);
            }
            if (lane == 0) atomicAdd(&cnt[curg], (float)rc);
            curg = g;
            p0 = p1 = p2 = p3 = p4 = p5 = p6 = p7 = 0.f;
            rc = 0;
        }
        __half2 A0, A1, A2, A3;
        A0 = A1 = A2 = A3 = __floats2half2_rn(0.f, 0.f);
        if (sub == 0) {
            uint4 sv = *(const uint4*)(Hs + (size_t)node * CH + c);
            A0 = h2(sv.x); A1 = h2(sv.y); A2 = h2(sv.z); A3 = h2(sv.w);
        }
        int mv = meta[node];
        int e0 = mv >> 7;
        int iters = mv & 127;
        for (int it = 0; it < iters; ++it) {
            int e = e0 + (it << 4) + sub;
            int s0 = ssrc[e];
            int s1 = ssrc[e + 4];
            int s2 = ssrc[e + 8];
            int s3 = ssrc[e + 12];
            uint4 g0 = *(const uint4*)(Hs + (size_t)s0 * CH + c);
            uint4 g1 = *(const uint4*)(Hs + (size_t)s1 * CH + c);
            uint4 g2 = *(const uint4*)(Hs + (size_t)s2 * CH + c);
            uint4 g3 = *(const uint4*)(Hs + (size_t)s3 * CH + c);
            A0 = __hadd2(A0, __hadd2(__hadd2(h2(g0.x), h2(g1.x)), __hadd2(h2(g2.x), h2(g3.x))));
            A1 = __hadd2(A1, __hadd2(__hadd2(h2(g0.y), h2(g1.y)), __hadd2(h2(g2.y), h2(g3.y))));
            A2 = __hadd2(A2, __hadd2(__hadd2(h2(g0.z), h2(g1.z)), __hadd2(h2(g2.z), h2(g3.z))));
            A3 = __hadd2(A3, __hadd2(__hadd2(h2(g0.w), h2(g1.w)), __hadd2(h2(g2.w), h2(g3.w))));
        }
        float2 f0 = __half22float2(A0);
        float2 f1 = __half22float2(A1);
        float2 f2 = __half22float2(A2);
        float2 f3 = __half22float2(A3);
        float v0 = f0.x, v1 = f0.y, v2 = f1.x, v3 = f1.y;
        float v4 = f2.x, v5 = f2.y, v6 = f3.x, v7 = f3.y;
        v0 += __shfl_xor(v0, 16); v0 += __shfl_xor(v0, 32);
        v1 += __shfl_xor(v1, 16); v1 += __shfl_xor(v1, 32);
        v2 += __shfl_xor(v2, 16); v2 += __shfl_xor(v2, 32);
        v3 += __shfl_xor(v3, 16); v3 += __shfl_xor(v3, 32);
        v4 += __shfl_xor(v4, 16); v4 += __shfl_xor(v4, 32);
        v5 += __shfl_xor(v5, 16); v5 += __shfl_xor(v5, 32);
        v6 += __shfl_xor(v6, 16); v6 += __shfl_xor(v6, 32);
        v7 += __shfl_xor(v7, 16); v7 += __shfl_xor(v7, 32);
        float d = dinv[node];
        p0 += v0 * d; p1 += v1 * d; p2 += v2 * d; p3 += v3 * d;
        p4 += v4 * d; p5 += v5 * d; p6 += v6 * d; p7 += v7 * d;
        rc++;
    }
    if (sub == 0) {
        atomicAdd(&Qs[curg * CH + c + 0], p0);
        atomicAdd(&Qs[curg * CH + c + 1], p1);
        atomicAdd(&Qs[curg * CH + c + 2], p2);
        atomicAdd(&Qs[curg * CH + c + 3], p3);
        atomicAdd(&Qs[curg * CH + c + 4], p4);
        atomicAdd(&Qs[curg * CH + c + 5], p5);
        atomicAdd(&Qs[curg * CH + c + 6], p6);
        atomicAdd(&Qs[curg * CH + c + 7], p7);
    }
    if (lane == 0) atomicAdd(&cnt[curg], (float)rc);
}

// ---------------- out = (Qs/cnt)*Wc + bc ----------------
__global__ __launch_bounds__(256) void k_out(const float* __restrict__ Qs,
                                             const float* __restrict__ cnt,
                                             const float* __restrict__ Wc,
                                             const float* __restrict__ bc,
                                             float* __restrict__ out) {
    int t = blockIdx.x * 256 + threadIdx.x;
    int g = t >> 6, o = t & 63;
    float invc = 1.f / fmaxf(cnt[g], 1.f);
    float acc = 0.f;
    for (int k = 0; k < CH; k++) acc += Qs[g * CH + k] * Wc[k * OC + o];
    out[t] = acc * invc + bc[o];
}

extern "C" void kernel_launch(void* const* d_in, const int* in_sizes, int n_in,
                              void* d_out, int out_size, void* d_ws, size_t ws_size,
                              hipStream_t stream) {
    const float* x   = (const float*)d_in[0];
    const float* W1  = (const float*)d_in[1];
    const float* b1  = (const float*)d_in[2];
    const float* W2  = (const float*)d_in[3];
    const float* b2  = (const float*)d_in[4];
    const float* Wfc = (const float*)d_in[5];
    const float* bfc = (const float*)d_in[6];
    const int* edges = (const int*)d_in[7];
    const int* batch = (const int*)d_in[8];

    const int n = in_sizes[8];        // 100000
    const int E = in_sizes[7] / 2;    // 1600000
    const int* esrc = edges;
    const int* edst = edges + E;

    const int NB = (n + 255) >> 8;            // 391 coarse buckets
    const int T = NB * NBLK;
    const int chunk = (E + NBLK - 1) / NBLK;

    char* p = (char*)d_ws;
    auto carve = [&](size_t bytes) {
        void* r = (void*)p;
        p += (bytes + 255) & ~(size_t)255;
        return r;
    };
    int*    bhT       = (int*)carve((size_t)T * 4);
    int*    off       = (int*)carve((size_t)T * 4);
    int*    bsums     = (int*)carve(512);
    int*    ebuf      = (int*)carve((size_t)E * 4);
    int*    meta      = (int*)carve((size_t)n * 4);
    float*  dinv      = (float*)carve((size_t)n * 4);
    int*    ssrc      = (int*)carve(((size_t)E + (size_t)NB * PADB) * 4);
    ushort* xb        = (ushort*)carve((size_t)(n + 1) * CH * 2);  // x pre-scaled
    ushort* yb        = (ushort*)carve((size_t)(n + 1) * CH * 2);  // h1s
    ushort* Wt        = (ushort*)carve((size_t)CH * CH * 2);
    float*  q         = (float*)carve((size_t)NG * CH * 4);
    float*  cnt       = (float*)carve((size_t)NG * 4);
    float*  Wc        = (float*)carve((size_t)CH * OC * 4);
    float*  bc        = (float*)carve((size_t)OC * 4);

    int nScanBlocks = (T + 1023) / 1024;
    int cvtBlocks = (n * CH / 4 + 255) / 256;
    int prepBlocks = (CH * CH + CH * OC + OC + 255) / 256;

    // CSR build (atomic-free global ordering, rows padded x16)
    k_hist<<<NBLK, 256, 0, stream>>>(edst, bhT, E, NB, chunk);
    k_scan1<<<nScanBlocks, 256, 0, stream>>>(bhT, off, bsums, T);
    k_scan2<<<1, 128, 0, stream>>>(bsums, nScanBlocks);
    k_part<<<NBLK, 256, 0, stream>>>(esrc, edst, off, bsums, ebuf, E, NB, chunk);
    k_csr<<<NB, 256, 0, stream>>>(ebuf, off, bsums, meta, dinv, ssrc, n, NB, E);

    // feature conversion + weight prep + q/cnt zero (one kernel)
    k_cvtprep<<<cvtBlocks + prepBlocks, 256, 0, stream>>>(
        x, dinv, W1, W2, b2, Wfc, bfc, xb, yb, Wt, Wc, bc, q, cnt, n, cvtBlocks);
    // h1s = fused agg1 + GEMM  (xb -> yb)
    k_aggemm<<<(n + 63) / 64, 256, 0, stream>>>(xb, meta, ssrc, dinv, Wt, b1, yb, n);
    // pooled sums = fused agg2 + pool  (yb -> q, cnt)
    k_agg2pool<<<(n + 31) / 32, 256, 0, stream>>>(yb, meta, ssrc, dinv, batch, q, cnt, n);
    // out = (q/cnt)*Wc + bc
    k_out<<<(NG * OC + 255) / 256, 256, 0, stream>>>(q, cnt, Wc, bc, (float*)d_out);
}